// Round 10
// baseline (289.481 us; speedup 1.0000x reference)
//
#include <hip/hip_runtime.h>
#include <hip/hip_bf16.h>

#define NROWS 4096
#define DIM   768
#define NKT   6           // 768 / 128 K-tiles

typedef __attribute__((ext_vector_type(4))) float f32x4;
typedef __attribute__((ext_vector_type(8))) int i32x8;

#define GAS(p) ((const __attribute__((address_space(1))) void*)(p))
#define SAS(p) ((__attribute__((address_space(3))) void*)(p))

// ---------------- Kernel 1: L2-normalize rows -> fp8 e4m3 (scaled x8); zero rowsum ----------------
__global__ __launch_bounds__(256) void k_norm(const float* __restrict__ f1,
                                              const float* __restrict__ f2,
                                              unsigned char* __restrict__ n1,
                                              unsigned char* __restrict__ n2,
                                              float* __restrict__ rowsum) {
    int b = blockIdx.x;
    int wid = threadIdx.x >> 6, lane = threadIdx.x & 63;
    int rowidx = b * 4 + wid;                     // 0..8191, wave-uniform
    const float* src = (rowidx < NROWS) ? f1 : f2;
    unsigned char* dst = (rowidx < NROWS) ? n1 : n2;
    int row = rowidx & (NROWS - 1);
    const float4* srow = (const float4*)(src + (size_t)row * DIM);
    float4 v[3];
    float ss = 0.f;
#pragma unroll
    for (int r = 0; r < 3; ++r) {
        v[r] = srow[lane + 64 * r];               // elements k = 4*lane + 256*r + {0..3}
        ss += v[r].x * v[r].x + v[r].y * v[r].y + v[r].z * v[r].z + v[r].w * v[r].w;
    }
#pragma unroll
    for (int off = 32; off; off >>= 1) ss += __shfl_xor(ss, off);
    float inv8 = 8.0f / fmaxf(sqrtf(ss), 1e-8f);  // x8 scale folded into the normalizer
    unsigned int* drow = (unsigned int*)(dst + (size_t)row * DIM);
#pragma unroll
    for (int r = 0; r < 3; ++r) {
        int w = __builtin_amdgcn_cvt_pk_fp8_f32(v[r].x * inv8, v[r].y * inv8, 0, false);
        w = __builtin_amdgcn_cvt_pk_fp8_f32(v[r].z * inv8, v[r].w * inv8, w, true);
        drow[lane + 64 * r] = (unsigned int)w;
    }
    if (b == 0) {                                  // zero rowsum (4096 floats)
        float4 z = {0.f, 0.f, 0.f, 0.f};
#pragma unroll
        for (int i = 0; i < 4; ++i) ((float4*)rowsum)[threadIdx.x + 256 * i] = z;
    }
}

// ---------------- Kernel 2: 128x128-tile MX-fp8 MFMA GEMM + fused exp/row-sum ----------------
// R9 structure byte-identical (32 KB single-buffer LDS, plain __syncthreads, 4 blocks/CU,
// 0-conflict XOR swizzle, global_load_lds 16B, XCD swizzle) with ONE change: the 64
// mfma_f32_16x16x32_fp8_fp8 per tile become 16 mfma_scale_f32_16x16x128_f8f6f4 (K=128 =
// whole LDS row per instruction) with unit scales (E8M0 0x7F = 2^0 in every byte -> opsel-
// proof; numerics identical to R9). A and B fragments are assembled with IDENTICAL
// (lane,reg)->k addressing, so any internal k-permutation of the operand layout cancels
// (same argument R1/R8 validated with absmax 0.0). MX rate: 4661 TF vs 2200 non-scaled.
__global__ __launch_bounds__(256, 4) void k_gemm_lse(const unsigned char* __restrict__ n1,
                                                     const unsigned char* __restrict__ n2,
                                                     float* __restrict__ rowsum,
                                                     float* __restrict__ diag) {
    __shared__ alignas(16) char ldsbuf[32768];
    char* ldsc = (char*)ldsbuf;

    // XCD-aware bijective swizzle (1024 % 8 == 0)
    int wg = blockIdx.x;
    int swz = (wg & 7) * 128 + (wg >> 3);
    int bi = swz >> 5;            // 32 i-tiles
    int bj = swz & 31;            // 32 j-tiles

    int tid = threadIdx.x;
    int wid = tid >> 6;
    int lane = tid & 63;
    int l15 = lane & 15, lk = lane >> 4;
    int wr = wid >> 1, wc = wid & 1;   // 2x2 wave grid, wave-tile 64x64

    const unsigned char* abase = n1 + (size_t)bi * 128 * DIM;
    const unsigned char* bbase = n2 + (size_t)bj * 128 * DIM;

    // staging: pre-swizzled global source, linear LDS dest (rule 21).
    const int stoff = (tid >> 3) * DIM + (((tid & 7) ^ ((tid >> 3) & 7)) * 16);

    // frag addressing (R8/R9-verified): j-slot s = 2j + (lk>>1), swizzled ^ (l15&7),
    // within-slot byte (lk&1)*8; each b64 stays inside one 16B swizzle unit.
    const int h7 = l15 & 7;
    const int fbase = l15 * 128 + (lk & 1) * 8;
    int slotx[4];
#pragma unroll
    for (int j = 0; j < 4; ++j) slotx[j] = ((2 * j + (lk >> 1)) ^ h7) * 16;

    // LDS: A [128 rows][128B] at 0 (this wave's half at wr*8192), B at 16384 (+wc*8192).
    const char* LAp = ldsc + wr * 8192;
    const char* LBp = ldsc + 16384 + wc * 8192;

#define STG1(isB, base, chunk, kt) do { \
    const unsigned char* _s = (base) + ((chunk) * 32) * DIM + (kt) * 128 + stoff; \
    char* _d = ldsc + (isB) * 16384 + (chunk) * 4096 + tid * 16; \
    __builtin_amdgcn_global_load_lds(GAS(_s), SAS(_d), 16, 0, 0); \
} while (0)

    f32x4 acc[4][4] = {};

    for (int t = 0; t < NKT; ++t) {
        STG1(0, abase, 0, t); STG1(0, abase, 1, t);
        STG1(0, abase, 2, t); STG1(0, abase, 3, t);
        STG1(1, bbase, 0, t); STG1(1, bbase, 1, t);
        STG1(1, bbase, 2, t); STG1(1, bbase, 3, t);
        __syncthreads();                 // drains vmcnt before any frag read

        // B fragments once per tile: 16 ds_read_b64 -> 4 x v8i32 (j-order packing)
        union { long l[4]; i32x8 v; } bu[4];
#pragma unroll
        for (int n = 0; n < 4; ++n)
#pragma unroll
            for (int j = 0; j < 4; ++j)
                bu[n].l[j] = *(const long*)(LBp + n * 2048 + fbase + slotx[j]);

#pragma unroll
        for (int m = 0; m < 4; ++m) {
            union { long l[4]; i32x8 v; } au;
#pragma unroll
            for (int j = 0; j < 4; ++j)
                au.l[j] = *(const long*)(LAp + m * 2048 + fbase + slotx[j]);
#pragma unroll
            for (int n = 0; n < 4; ++n)
                acc[m][n] = __builtin_amdgcn_mfma_scale_f32_16x16x128_f8f6f4(
                                au.v, bu[n].v, acc[m][n],
                                0, 0,                  // cbsz=fp8(A), blgp=fp8(B)
                                0, 0x7F7F7F7F,         // opsel_a, scale_a = 1.0 (all bytes)
                                0, 0x7F7F7F7F);        // opsel_b, scale_b = 1.0
        }
        __syncthreads();                 // protect LDS before next tile's staging
    }

    // Epilogue. C/D layout: col = l15, row = lk*4 + r (shape-determined, m127/m128).
    // acc = (8a)(8b) = 64*cossim -> logits = acc * (20/64).
    const bool dblk = (bi == bj);
    const int rowb = bi * 128 + wr * 64;
    const int colb = bj * 128 + wc * 64;
#pragma unroll
    for (int mi = 0; mi < 4; ++mi) {
#pragma unroll
        for (int r = 0; r < 4; ++r) {
            float s = 0.f;
            int gi = rowb + mi * 16 + lk * 4 + r;
#pragma unroll
            for (int ni = 0; ni < 4; ++ni) {
                float v = acc[mi][ni][r] * (20.0f / 64.0f);
                s += __expf(v);
                if (dblk) {
                    int gj = colb + ni * 16 + l15;
                    if (gi == gj) diag[gi] = v;
                }
            }
#pragma unroll
            for (int off = 1; off < 16; off <<= 1) s += __shfl_xor(s, off);
            if (l15 == 0) atomicAdd(rowsum + gi, s);
        }
    }
}

// ---------------- Kernel 3: loss = mean(log(rowsum) - diag) ----------------
__global__ __launch_bounds__(1024) void k_final(const float* __restrict__ rowsum,
                                                const float* __restrict__ diag,
                                                float* __restrict__ out) {
    int tid = threadIdx.x;
    float s = 0.f;
#pragma unroll
    for (int i = 0; i < 4; ++i) {
        int idx = tid + 1024 * i;
        s += logf(rowsum[idx]) - diag[idx];
    }
#pragma unroll
    for (int off = 32; off; off >>= 1) s += __shfl_xor(s, off);
    __shared__ float red[16];
    if ((tid & 63) == 0) red[tid >> 6] = s;
    __syncthreads();
    if (tid == 0) {
        float tot = 0.f;
#pragma unroll
        for (int i = 0; i < 16; ++i) tot += red[i];
        out[0] = tot * (1.0f / NROWS);
    }
}

extern "C" void kernel_launch(void* const* d_in, const int* in_sizes, int n_in,
                              void* d_out, int out_size, void* d_ws, size_t ws_size,
                              hipStream_t stream) {
    const float* f1 = (const float*)d_in[0];
    const float* f2 = (const float*)d_in[1];
    float* out = (float*)d_out;

    char* ws = (char*)d_ws;                       // layout: n1 | n2 | rowsum | diag
    unsigned char* n1 = (unsigned char*)ws;
    unsigned char* n2 = n1 + (size_t)NROWS * DIM;
    float* rowsum = (float*)(ws + 2 * (size_t)NROWS * DIM);
    float* diag = rowsum + NROWS;

    k_norm<<<2048, 256, 0, stream>>>(f1, f2, n1, n2, rowsum);
    k_gemm_lse<<<1024, 256, 0, stream>>>(n1, n2, rowsum, diag);
    k_final<<<1, 1024, 0, stream>>>(rowsum, diag, out);
}

// Round 11
// 289.187 us; speedup vs baseline: 1.0010x; 1.0010x over previous
//
#include <hip/hip_runtime.h>
#include <hip/hip_bf16.h>

#define NROWS 4096
#define DIM   768
#define NKT   6           // 768 / 128 K-tiles

typedef __attribute__((ext_vector_type(4))) float f32x4;
typedef __attribute__((ext_vector_type(8))) int i32x8;

#define GAS(p) ((const __attribute__((address_space(1))) void*)(p))
#define SAS(p) ((__attribute__((address_space(3))) void*)(p))

// ---------------- Kernel 1: L2-normalize rows -> fp8 e4m3 (scaled x8); zero rowsum ----------------
__global__ __launch_bounds__(256) void k_norm(const float* __restrict__ f1,
                                              const float* __restrict__ f2,
                                              unsigned char* __restrict__ n1,
                                              unsigned char* __restrict__ n2,
                                              float* __restrict__ rowsum) {
    int b = blockIdx.x;
    int wid = threadIdx.x >> 6, lane = threadIdx.x & 63;
    int rowidx = b * 4 + wid;                     // 0..8191, wave-uniform
    const float* src = (rowidx < NROWS) ? f1 : f2;
    unsigned char* dst = (rowidx < NROWS) ? n1 : n2;
    int row = rowidx & (NROWS - 1);
    const float4* srow = (const float4*)(src + (size_t)row * DIM);
    float4 v[3];
    float ss = 0.f;
#pragma unroll
    for (int r = 0; r < 3; ++r) {
        v[r] = srow[lane + 64 * r];               // elements k = 4*lane + 256*r + {0..3}
        ss += v[r].x * v[r].x + v[r].y * v[r].y + v[r].z * v[r].z + v[r].w * v[r].w;
    }
#pragma unroll
    for (int off = 32; off; off >>= 1) ss += __shfl_xor(ss, off);
    float inv8 = 8.0f / fmaxf(sqrtf(ss), 1e-8f);  // x8 scale folded into the normalizer
    unsigned int* drow = (unsigned int*)(dst + (size_t)row * DIM);
#pragma unroll
    for (int r = 0; r < 3; ++r) {
        int w = __builtin_amdgcn_cvt_pk_fp8_f32(v[r].x * inv8, v[r].y * inv8, 0, false);
        w = __builtin_amdgcn_cvt_pk_fp8_f32(v[r].z * inv8, v[r].w * inv8, w, true);
        drow[lane + 64 * r] = (unsigned int)w;
    }
    if (b == 0) {                                  // zero rowsum (4096 floats)
        float4 z = {0.f, 0.f, 0.f, 0.f};
#pragma unroll
        for (int i = 0; i < 4; ++i) ((float4*)rowsum)[threadIdx.x + 256 * i] = z;
    }
}

// ---------------- Kernel 2: 128x128-tile MX-fp8 MFMA GEMM + fused exp/row-sum ----------------
// R10 retry with the spill removed: operand i32x8s are NAMED vector registers built with
// compile-time-constant element inserts (no unions, no arrays-of-vectors -> no scratch).
// Structure/numerics byte-identical to R10 (which verified absmax 0.0): 32 KB single-buffer
// LDS, plain __syncthreads, 4 blocks/CU, XOR swizzle, global_load_lds 16B, XCD swizzle,
// mfma_scale_f32_16x16x128_f8f6f4 with unit E8M0 scales (0x7F bytes).
__global__ __launch_bounds__(256, 4) void k_gemm_lse(const unsigned char* __restrict__ n1,
                                                     const unsigned char* __restrict__ n2,
                                                     float* __restrict__ rowsum,
                                                     float* __restrict__ diag) {
    __shared__ alignas(16) char ldsbuf[32768];
    char* ldsc = (char*)ldsbuf;

    // XCD-aware bijective swizzle (1024 % 8 == 0)
    int wg = blockIdx.x;
    int swz = (wg & 7) * 128 + (wg >> 3);
    int bi = swz >> 5;            // 32 i-tiles
    int bj = swz & 31;            // 32 j-tiles

    int tid = threadIdx.x;
    int wid = tid >> 6;
    int lane = tid & 63;
    int l15 = lane & 15, lk = lane >> 4;
    int wr = wid >> 1, wc = wid & 1;   // 2x2 wave grid, wave-tile 64x64

    const unsigned char* abase = n1 + (size_t)bi * 128 * DIM;
    const unsigned char* bbase = n2 + (size_t)bj * 128 * DIM;

    // staging: pre-swizzled global source, linear LDS dest (rule 21).
    const int stoff = (tid >> 3) * DIM + (((tid & 7) ^ ((tid >> 3) & 7)) * 16);

    // frag addressing (R8/R9/R10-verified): j-slot s = 2j + (lk>>1), swizzled ^ (l15&7),
    // within-slot byte (lk&1)*8; each b64 stays inside one 16B swizzle unit.
    const int h7 = l15 & 7;
    const int fbase = l15 * 128 + (lk & 1) * 8;
    int slotx[4];
#pragma unroll
    for (int j = 0; j < 4; ++j) slotx[j] = ((2 * j + (lk >> 1)) ^ h7) * 16;

    // LDS: A [128 rows][128B] at 0 (this wave's half at wr*8192), B at 16384 (+wc*8192).
    const char* LAp = ldsc + wr * 8192;
    const char* LBp = ldsc + 16384 + wc * 8192;

#define STG1(isB, base, chunk, kt) do { \
    const unsigned char* _s = (base) + ((chunk) * 32) * DIM + (kt) * 128 + stoff; \
    char* _d = ldsc + (isB) * 16384 + (chunk) * 4096 + tid * 16; \
    __builtin_amdgcn_global_load_lds(GAS(_s), SAS(_d), 16, 0, 0); \
} while (0)

// build one i32x8 operand from 4 ds_read_b64 (int2) -- ALL element indices compile-time
#define LDV8(Pbase, roff, dstv) do { _Pragma("unroll") for (int j = 0; j < 4; ++j) { \
    int2 _q = *(const int2*)((Pbase) + (roff) + fbase + slotx[j]); \
    dstv[2 * j] = _q.x; dstv[2 * j + 1] = _q.y; } } while (0)

#define MXMFMA(av, bv, c) \
    c = __builtin_amdgcn_mfma_scale_f32_16x16x128_f8f6f4( \
            av, bv, c, 0, 0, 0, 0x7F7F7F7F, 0, 0x7F7F7F7F)

    f32x4 acc[4][4] = {};

    for (int t = 0; t < NKT; ++t) {
        STG1(0, abase, 0, t); STG1(0, abase, 1, t);
        STG1(0, abase, 2, t); STG1(0, abase, 3, t);
        STG1(1, bbase, 0, t); STG1(1, bbase, 1, t);
        STG1(1, bbase, 2, t); STG1(1, bbase, 3, t);
        __syncthreads();                 // drains vmcnt before any frag read

        i32x8 bv0, bv1, bv2, bv3;        // named registers (no scratch)
        LDV8(LBp, 0 * 2048, bv0);
        LDV8(LBp, 1 * 2048, bv1);
        LDV8(LBp, 2 * 2048, bv2);
        LDV8(LBp, 3 * 2048, bv3);
#pragma unroll
        for (int m = 0; m < 4; ++m) {
            i32x8 av;
            LDV8(LAp, m * 2048, av);
            MXMFMA(av, bv0, acc[m][0]);
            MXMFMA(av, bv1, acc[m][1]);
            MXMFMA(av, bv2, acc[m][2]);
            MXMFMA(av, bv3, acc[m][3]);
        }
        __syncthreads();                 // protect LDS before next tile's staging
    }

    // Epilogue. C/D layout: col = l15, row = lk*4 + r (shape-determined, m127/m128).
    // acc = (8a)(8b) = 64*cossim -> logits = acc * (20/64).
    const bool dblk = (bi == bj);
    const int rowb = bi * 128 + wr * 64;
    const int colb = bj * 128 + wc * 64;
#pragma unroll
    for (int mi = 0; mi < 4; ++mi) {
#pragma unroll
        for (int r = 0; r < 4; ++r) {
            float s = 0.f;
            int gi = rowb + mi * 16 + lk * 4 + r;
#pragma unroll
            for (int ni = 0; ni < 4; ++ni) {
                float v = acc[mi][ni][r] * (20.0f / 64.0f);
                s += __expf(v);
                if (dblk) {
                    int gj = colb + ni * 16 + l15;
                    if (gi == gj) diag[gi] = v;
                }
            }
#pragma unroll
            for (int off = 1; off < 16; off <<= 1) s += __shfl_xor(s, off);
            if (l15 == 0) atomicAdd(rowsum + gi, s);
        }
    }
}

// ---------------- Kernel 3: loss = mean(log(rowsum) - diag) ----------------
__global__ __launch_bounds__(1024) void k_final(const float* __restrict__ rowsum,
                                                const float* __restrict__ diag,
                                                float* __restrict__ out) {
    int tid = threadIdx.x;
    float s = 0.f;
#pragma unroll
    for (int i = 0; i < 4; ++i) {
        int idx = tid + 1024 * i;
        s += logf(rowsum[idx]) - diag[idx];
    }
#pragma unroll
    for (int off = 32; off; off >>= 1) s += __shfl_xor(s, off);
    __shared__ float red[16];
    if ((tid & 63) == 0) red[tid >> 6] = s;
    __syncthreads();
    if (tid == 0) {
        float tot = 0.f;
#pragma unroll
        for (int i = 0; i < 16; ++i) tot += red[i];
        out[0] = tot * (1.0f / NROWS);
    }
}

extern "C" void kernel_launch(void* const* d_in, const int* in_sizes, int n_in,
                              void* d_out, int out_size, void* d_ws, size_t ws_size,
                              hipStream_t stream) {
    const float* f1 = (const float*)d_in[0];
    const float* f2 = (const float*)d_in[1];
    float* out = (float*)d_out;

    char* ws = (char*)d_ws;                       // layout: n1 | n2 | rowsum | diag
    unsigned char* n1 = (unsigned char*)ws;
    unsigned char* n2 = n1 + (size_t)NROWS * DIM;
    float* rowsum = (float*)(ws + 2 * (size_t)NROWS * DIM);
    float* diag = rowsum + NROWS;

    k_norm<<<2048, 256, 0, stream>>>(f1, f2, n1, n2, rowsum);
    k_gemm_lse<<<1024, 256, 0, stream>>>(n1, n2, rowsum, diag);
    k_final<<<1, 1024, 0, stream>>>(rowsum, diag, out);
}

// Round 12
// 220.962 us; speedup vs baseline: 1.3101x; 1.3088x over previous
//
#include <hip/hip_runtime.h>
#include <hip/hip_bf16.h>

#define NROWS 4096
#define DIM   768
#define NKT   6           // 768 / 128 K-tiles

typedef __attribute__((ext_vector_type(4))) float f32x4;
typedef __attribute__((ext_vector_type(8))) int i32x8;

#define GAS(p) ((const __attribute__((address_space(1))) void*)(p))
#define SAS(p) ((__attribute__((address_space(3))) void*)(p))

// ---------------- Kernel 1: L2-normalize rows -> fp8 e4m3 (scaled x8); zero rowsum ----------------
__global__ __launch_bounds__(256) void k_norm(const float* __restrict__ f1,
                                              const float* __restrict__ f2,
                                              unsigned char* __restrict__ n1,
                                              unsigned char* __restrict__ n2,
                                              float* __restrict__ rowsum) {
    int b = blockIdx.x;
    int wid = threadIdx.x >> 6, lane = threadIdx.x & 63;
    int rowidx = b * 4 + wid;                     // 0..8191, wave-uniform
    const float* src = (rowidx < NROWS) ? f1 : f2;
    unsigned char* dst = (rowidx < NROWS) ? n1 : n2;
    int row = rowidx & (NROWS - 1);
    const float4* srow = (const float4*)(src + (size_t)row * DIM);
    float4 v[3];
    float ss = 0.f;
#pragma unroll
    for (int r = 0; r < 3; ++r) {
        v[r] = srow[lane + 64 * r];               // elements k = 4*lane + 256*r + {0..3}
        ss += v[r].x * v[r].x + v[r].y * v[r].y + v[r].z * v[r].z + v[r].w * v[r].w;
    }
#pragma unroll
    for (int off = 32; off; off >>= 1) ss += __shfl_xor(ss, off);
    float inv8 = 8.0f / fmaxf(sqrtf(ss), 1e-8f);  // x8 scale folded into the normalizer
    unsigned int* drow = (unsigned int*)(dst + (size_t)row * DIM);
#pragma unroll
    for (int r = 0; r < 3; ++r) {
        int w = __builtin_amdgcn_cvt_pk_fp8_f32(v[r].x * inv8, v[r].y * inv8, 0, false);
        w = __builtin_amdgcn_cvt_pk_fp8_f32(v[r].z * inv8, v[r].w * inv8, w, true);
        drow[lane + 64 * r] = (unsigned int)w;
    }
    if (b == 0) {                                  // zero rowsum (4096 floats)
        float4 z = {0.f, 0.f, 0.f, 0.f};
#pragma unroll
        for (int i = 0; i < 4; ++i) ((float4*)rowsum)[threadIdx.x + 256 * i] = z;
    }
}

// ---------------- Kernel 2: 128x128-tile MX-fp8 MFMA GEMM + fused exp/row-sum ----------------
// R11 with the spill's ROOT CAUSE fixed: register demand (~135: acc 64 + bv 32 + av 8 +
// addressing ~30) exceeded the 128-VGPR cap implied by __launch_bounds__(256,4) -> allocator
// spilled the MFMA operand chain to scratch (VGPR=64, WRITE 287MB, 214us). Cap relaxed to
// (256,3): ~170 VGPRs, 3 blocks/CU -- the m97 occupancy point (874 TF with this structure,
// and m148/m153 ran these MX intrinsics cleanly with no min-waves bound). All else identical.
__global__ __launch_bounds__(256, 3) void k_gemm_lse(const unsigned char* __restrict__ n1,
                                                     const unsigned char* __restrict__ n2,
                                                     float* __restrict__ rowsum,
                                                     float* __restrict__ diag) {
    __shared__ alignas(16) char ldsbuf[32768];
    char* ldsc = (char*)ldsbuf;

    // XCD-aware bijective swizzle (1024 % 8 == 0)
    int wg = blockIdx.x;
    int swz = (wg & 7) * 128 + (wg >> 3);
    int bi = swz >> 5;            // 32 i-tiles
    int bj = swz & 31;            // 32 j-tiles

    int tid = threadIdx.x;
    int wid = tid >> 6;
    int lane = tid & 63;
    int l15 = lane & 15, lk = lane >> 4;
    int wr = wid >> 1, wc = wid & 1;   // 2x2 wave grid, wave-tile 64x64

    const unsigned char* abase = n1 + (size_t)bi * 128 * DIM;
    const unsigned char* bbase = n2 + (size_t)bj * 128 * DIM;

    // staging: pre-swizzled global source, linear LDS dest (rule 21).
    const int stoff = (tid >> 3) * DIM + (((tid & 7) ^ ((tid >> 3) & 7)) * 16);

    // frag addressing (R8/R9-verified): j-slot s = 2j + (lk>>1), swizzled ^ (l15&7),
    // within-slot byte (lk&1)*8; each b64 stays inside one 16B swizzle unit.
    const int h7 = l15 & 7;
    const int fbase = l15 * 128 + (lk & 1) * 8;
    int slotx[4];
#pragma unroll
    for (int j = 0; j < 4; ++j) slotx[j] = ((2 * j + (lk >> 1)) ^ h7) * 16;

    // LDS: A [128 rows][128B] at 0 (this wave's half at wr*8192), B at 16384 (+wc*8192).
    const char* LAp = ldsc + wr * 8192;
    const char* LBp = ldsc + 16384 + wc * 8192;

#define STG1(isB, base, chunk, kt) do { \
    const unsigned char* _s = (base) + ((chunk) * 32) * DIM + (kt) * 128 + stoff; \
    char* _d = ldsc + (isB) * 16384 + (chunk) * 4096 + tid * 16; \
    __builtin_amdgcn_global_load_lds(GAS(_s), SAS(_d), 16, 0, 0); \
} while (0)

// build one i32x8 operand from 4 ds_read_b64 (int2) -- ALL element indices compile-time
#define LDV8(Pbase, roff, dstv) do { _Pragma("unroll") for (int j = 0; j < 4; ++j) { \
    int2 _q = *(const int2*)((Pbase) + (roff) + fbase + slotx[j]); \
    dstv[2 * j] = _q.x; dstv[2 * j + 1] = _q.y; } } while (0)

#define MXMFMA(av, bv, c) \
    c = __builtin_amdgcn_mfma_scale_f32_16x16x128_f8f6f4( \
            av, bv, c, 0, 0, 0, 0x7F7F7F7F, 0, 0x7F7F7F7F)

    f32x4 acc[4][4] = {};

    for (int t = 0; t < NKT; ++t) {
        STG1(0, abase, 0, t); STG1(0, abase, 1, t);
        STG1(0, abase, 2, t); STG1(0, abase, 3, t);
        STG1(1, bbase, 0, t); STG1(1, bbase, 1, t);
        STG1(1, bbase, 2, t); STG1(1, bbase, 3, t);
        __syncthreads();                 // drains vmcnt before any frag read

        i32x8 bv0, bv1, bv2, bv3;        // named registers
        LDV8(LBp, 0 * 2048, bv0);
        LDV8(LBp, 1 * 2048, bv1);
        LDV8(LBp, 2 * 2048, bv2);
        LDV8(LBp, 3 * 2048, bv3);
#pragma unroll
        for (int m = 0; m < 4; ++m) {
            i32x8 av;
            LDV8(LAp, m * 2048, av);
            MXMFMA(av, bv0, acc[m][0]);
            MXMFMA(av, bv1, acc[m][1]);
            MXMFMA(av, bv2, acc[m][2]);
            MXMFMA(av, bv3, acc[m][3]);
        }
        __syncthreads();                 // protect LDS before next tile's staging
    }

    // Epilogue. C/D layout: col = l15, row = lk*4 + r (shape-determined, m127/m128).
    // acc = (8a)(8b) = 64*cossim -> logits = acc * (20/64).
    const bool dblk = (bi == bj);
    const int rowb = bi * 128 + wr * 64;
    const int colb = bj * 128 + wc * 64;
#pragma unroll
    for (int mi = 0; mi < 4; ++mi) {
#pragma unroll
        for (int r = 0; r < 4; ++r) {
            float s = 0.f;
            int gi = rowb + mi * 16 + lk * 4 + r;
#pragma unroll
            for (int ni = 0; ni < 4; ++ni) {
                float v = acc[mi][ni][r] * (20.0f / 64.0f);
                s += __expf(v);
                if (dblk) {
                    int gj = colb + ni * 16 + l15;
                    if (gi == gj) diag[gi] = v;
                }
            }
#pragma unroll
            for (int off = 1; off < 16; off <<= 1) s += __shfl_xor(s, off);
            if (l15 == 0) atomicAdd(rowsum + gi, s);
        }
    }
}

// ---------------- Kernel 3: loss = mean(log(rowsum) - diag) ----------------
__global__ __launch_bounds__(1024) void k_final(const float* __restrict__ rowsum,
                                                const float* __restrict__ diag,
                                                float* __restrict__ out) {
    int tid = threadIdx.x;
    float s = 0.f;
#pragma unroll
    for (int i = 0; i < 4; ++i) {
        int idx = tid + 1024 * i;
        s += logf(rowsum[idx]) - diag[idx];
    }
#pragma unroll
    for (int off = 32; off; off >>= 1) s += __shfl_xor(s, off);
    __shared__ float red[16];
    if ((tid & 63) == 0) red[tid >> 6] = s;
    __syncthreads();
    if (tid == 0) {
        float tot = 0.f;
#pragma unroll
        for (int i = 0; i < 16; ++i) tot += red[i];
        out[0] = tot * (1.0f / NROWS);
    }
}

extern "C" void kernel_launch(void* const* d_in, const int* in_sizes, int n_in,
                              void* d_out, int out_size, void* d_ws, size_t ws_size,
                              hipStream_t stream) {
    const float* f1 = (const float*)d_in[0];
    const float* f2 = (const float*)d_in[1];
    float* out = (float*)d_out;

    char* ws = (char*)d_ws;                       // layout: n1 | n2 | rowsum | diag
    unsigned char* n1 = (unsigned char*)ws;
    unsigned char* n2 = n1 + (size_t)NROWS * DIM;
    float* rowsum = (float*)(ws + 2 * (size_t)NROWS * DIM);
    float* diag = rowsum + NROWS;

    k_norm<<<2048, 256, 0, stream>>>(f1, f2, n1, n2, rowsum);
    k_gemm_lse<<<1024, 256, 0, stream>>>(n1, n2, rowsum, diag);
    k_final<<<1, 1024, 0, stream>>>(rowsum, diag, out);
}